// Round 25
// baseline (279.993 us; speedup 1.0000x reference)
//
#include <hip/hip_runtime.h>
#include <hip/hip_bf16.h>

// Problem sizes (fixed by the reference)
#define S_LEN 256     // sequence length (t)
#define DM    512     // d_model (k / d)
#define DR    512     // d_rnn (s)

#define NBLK_GEMM 2048
#define NBLK_REC  256

typedef float f4 __attribute__((ext_vector_type(4)));
typedef float f2 __attribute__((ext_vector_type(2)));

// ws layout (floats):
//   xT    : [512][256]        at 0        (131072)
//   part  : [8][1024][256]    at 131072   (2097152)
//   flags : int[256]          at 2228224

__global__ __launch_bounds__(256) void k_zero_flags(int* __restrict__ flags) {
    flags[threadIdx.x] = 0;
}

__global__ __launch_bounds__(256) void k_transpose_x(const float* __restrict__ x,
                                                     float* __restrict__ xT) {
    __shared__ float tile[32][33];
    const int k0 = blockIdx.x * 32;
    const int t0 = blockIdx.y * 32;
    const int lx = threadIdx.x & 31;
    const int ly = threadIdx.x >> 5;
#pragma unroll
    for (int i = 0; i < 32; i += 8)
        tile[ly + i][lx] = x[(t0 + ly + i) * DM + k0 + lx];
    __syncthreads();
#pragma unroll
    for (int i = 0; i < 32; i += 8)
        xT[(k0 + ly + i) * S_LEN + t0 + lx] = tile[lx][ly + i];
}

// ===== R25: producer-consumer mega-kernel =====
// Blocks 0..2047: gemm role (R21's k_gemm body). After storing its 4 partial
// rows, each block releases flags[sp] (fence + syncthreads + release atomic).
// Blocks 2048..2303: rec role (R21's k_rec body). Spins (relaxed agent loads,
// s_sleep backoff) until its s-pair's 8 producers signal, then acquires and
// runs the act-fold + y-stream. Early s-pairs' rec overlaps late gemm blocks,
// hiding the ~18us gemm+cold region under the store stream.
// Deadlock-free: producers never wait; 256 consumers < resident-block slots.
__global__ __launch_bounds__(256) void k_mega(const float* __restrict__ xT,
                                              const float* __restrict__ W1,
                                              const float* __restrict__ x,
                                              const float* __restrict__ state0,
                                              const float* __restrict__ b1,
                                              const float* __restrict__ Lam,
                                              float* __restrict__ part,
                                              int* __restrict__ flags,
                                              f4* __restrict__ out4) {
    const int bx  = blockIdx.x;
    const int tid = threadIdx.x;
    const int P   = 1024 * 256;

    if (bx < NBLK_GEMM) {
        // ---------------- gemm role ----------------
        const int sp = bx >> 3;           // s-pair 0..255
        const int ke = bx & 7;            // k-eighth 0..7
        const int t  = tid;

        const int r0 = 2 * sp, r1 = 2 * sp + 1;
        const int r2 = DR + 2 * sp, r3 = DR + 2 * sp + 1;

        const f4* __restrict__ W0 = reinterpret_cast<const f4*>(W1 + r0 * DM + ke * 64);
        const f4* __restrict__ Wp = reinterpret_cast<const f4*>(W1 + r1 * DM + ke * 64);
        const f4* __restrict__ W2 = reinterpret_cast<const f4*>(W1 + r2 * DM + ke * 64);
        const f4* __restrict__ W3 = reinterpret_cast<const f4*>(W1 + r3 * DM + ke * 64);
        const float* __restrict__ xb = xT + (ke * 64) * S_LEN + t;

        float a0 = 0.f, a1 = 0.f, a2 = 0.f, a3 = 0.f;

#pragma unroll 4
        for (int kk = 0; kk < 16; ++kk) {
            const float x0 = xb[(4 * kk + 0) * S_LEN];   // coalesced (lane = t)
            const float x1 = xb[(4 * kk + 1) * S_LEN];
            const float x2 = xb[(4 * kk + 2) * S_LEN];
            const float x3 = xb[(4 * kk + 3) * S_LEN];
            const f4 w0 = W0[kk];                        // wave-uniform -> s_load
            const f4 w1 = Wp[kk];
            const f4 w2 = W2[kk];
            const f4 w3 = W3[kk];
            a0 = fmaf(x0, w0.x, a0); a0 = fmaf(x1, w0.y, a0);
            a0 = fmaf(x2, w0.z, a0); a0 = fmaf(x3, w0.w, a0);
            a1 = fmaf(x0, w1.x, a1); a1 = fmaf(x1, w1.y, a1);
            a1 = fmaf(x2, w1.z, a1); a1 = fmaf(x3, w1.w, a1);
            a2 = fmaf(x0, w2.x, a2); a2 = fmaf(x1, w2.y, a2);
            a2 = fmaf(x2, w2.z, a2); a2 = fmaf(x3, w2.w, a2);
            a3 = fmaf(x0, w3.x, a3); a3 = fmaf(x1, w3.y, a3);
            a3 = fmaf(x2, w3.z, a3); a3 = fmaf(x3, w3.w, a3);
        }

        float* __restrict__ pb = part + ke * P;
        pb[r0 * 256 + t] = a0;                           // coalesced
        pb[r1 * 256 + t] = a1;
        pb[r2 * 256 + t] = a2;
        pb[r3 * 256 + t] = a3;

        __threadfence();                 // each thread's stores visible device-wide
        __syncthreads();                 // all threads' stores fenced
        if (tid == 0)
            __hip_atomic_fetch_add(&flags[sp], 1, __ATOMIC_RELEASE,
                                   __HIP_MEMORY_SCOPE_AGENT);
        return;
    }

    // ---------------- rec role ----------------
    const int rb   = bx - NBLK_GEMM;
    const int sp   = (rb & 7) * 32 + (rb >> 3);   // bijective XCD s-banding
    const int half = tid >> 7;           // 0 or 1
    const int s    = sp * 2 + half;
    const int dq   = tid & 127;          // d/4

    __shared__ f2 ac_l[2][S_LEN];        // {a, c} per (half, t)

    // loads independent of part can start before the spin
    const f4* __restrict__ st4 = reinterpret_cast<const f4*>(state0);
    f4 h = st4[s * 128 + dq];
    const f4* __restrict__ x4 = reinterpret_cast<const f4*>(x);
    f4 xv = x4[dq];                      // t = 0 prefetch

    if (tid == 0) {
        while (__hip_atomic_load(&flags[sp], __ATOMIC_RELAXED,
                                 __HIP_MEMORY_SCOPE_AGENT) < 8)
            __builtin_amdgcn_s_sleep(8);
        (void)__hip_atomic_load(&flags[sp], __ATOMIC_ACQUIRE,
                                __HIP_MEMORY_SCOPE_AGENT);   // invalidate caches
    }
    __syncthreads();

    // ---- folded act: reduce 8 k-partials + activations -> ac_l ----
#pragma unroll
    for (int sl = 0; sl < 2; ++sl) {
        const int srow = sp * 2 + sl;
        float pi = b1[srow];
        float pr = b1[DR + srow];
#pragma unroll
        for (int e = 0; e < 8; ++e) {
            pi += part[e * P + srow * 256 + tid];          // coalesced
            pr += part[e * P + (DR + srow) * 256 + tid];
        }
        const float inp = 1.f / (1.f + expf(-pi));         // sigmoid
        const float rec = 1.f / (1.f + expf(-pr));         // sigmoid
        const float sof = log1pf(expf(Lam[srow]));         // softplus
        const float a   = expf(-8.f * sof * rec);
        const float c   = sqrtf(fmaxf(1.f - a * a, 0.f)) * inp;
        f2 ac; ac.x = a; ac.y = c;
        ac_l[sl][tid] = ac;
    }
    __syncthreads();                     // ac_l ready

#pragma unroll 4
    for (int t = 0; t < S_LEN; ++t) {
        f4 xn;
        if (t + 1 < S_LEN) xn = x4[(t + 1) * 128 + dq];
        else xn = (f4)0.f;

        const f2 ac = ac_l[half][t];               // LDS broadcast (wave-uniform)
        const float at = ac.x, ct = ac.y;
        h.x = fmaf(at, h.x, ct * xv.x);
        h.y = fmaf(at, h.y, ct * xv.y);
        h.z = fmaf(at, h.z, ct * xv.z);
        h.w = fmaf(at, h.w, ct * xv.w);

        __builtin_nontemporal_store(h, &out4[(t * DR + s) * 128 + dq]);
        xv = xn;
    }
    // final state
    out4[(S_LEN * DR) * 128 + s * 128 + dq] = h;
}

extern "C" void kernel_launch(void* const* d_in, const int* in_sizes, int n_in,
                              void* d_out, int out_size, void* d_ws, size_t ws_size,
                              hipStream_t stream) {
    const float* x      = (const float*)d_in[0];
    const float* state0 = (const float*)d_in[1];
    const float* W1     = (const float*)d_in[2];
    const float* b1     = (const float*)d_in[3];
    const float* Lam    = (const float*)d_in[4];

    float* ws    = (float*)d_ws;
    float* xT    = ws;                        // 131072 floats
    float* part  = ws + 131072;               // 2097152 floats
    int*   flags = (int*)(ws + 2228224);      // 256 ints

    f4* out4 = (f4*)d_out;

    k_zero_flags<<<dim3(1), 256, 0, stream>>>(flags);
    k_transpose_x<<<dim3(16, 8), 256, 0, stream>>>(x, xT);
    k_mega<<<dim3(NBLK_GEMM + NBLK_REC), 256, 0, stream>>>(
        xT, W1, x, state0, b1, Lam, part, flags, out4);
}

// Round 26
// 63.928 us; speedup vs baseline: 4.3799x; 4.3799x over previous
//
#include <hip/hip_runtime.h>
#include <hip/hip_bf16.h>

// Problem sizes (fixed by the reference)
#define S_LEN 256     // sequence length (t)
#define DM    512     // d_model (k / d)
#define DR    512     // d_rnn (s)

typedef float f4 __attribute__((ext_vector_type(4)));
typedef float f2 __attribute__((ext_vector_type(2)));

// ws layout (floats):
//   xT   : [512][256]        at 0        (131072)
//   part : [8][1024][256]    at 131072   (2097152)

// XCD-ALIGNED transpose (the only change vs R21): 1-D grid of 128; block bx
// handles k-range of eighth ke = bx%8, so (XCD = bx%8 round-robin) the writer
// of xT slice ke runs on XCD ke. k_gemm's readers of slice ke are exactly the
// blocks with bx%8 == ke (bx = sp*8+ke) -> same XCD -> the 128 MB of xT
// re-reads become local-L2 hits instead of cross-XCD L3 misses (the measured
// ~9us cold-gemm penalty: slice ke was previously written by XCDs 2ke, 2ke+1).
__global__ __launch_bounds__(256) void k_transpose_x(const float* __restrict__ x,
                                                     float* __restrict__ xT) {
    __shared__ float tile[32][33];
    const int bx = blockIdx.x;              // 0..127
    const int ke = bx & 7;                  // k-eighth; == this block's XCD
    const int sub = bx >> 3;                // 0..15
    const int kh = sub & 1;                 // k-half within the eighth
    const int tt = sub >> 1;                // t-tile 0..7
    const int k0 = ke * 64 + kh * 32;
    const int t0 = tt * 32;
    const int lx = threadIdx.x & 31;
    const int ly = threadIdx.x >> 5;
#pragma unroll
    for (int i = 0; i < 32; i += 8)
        tile[ly + i][lx] = x[(t0 + ly + i) * DM + k0 + lx];
    __syncthreads();
#pragma unroll
    for (int i = 0; i < 32; i += 8)
        xT[(k0 + ly + i) * S_LEN + t0 + lx] = tile[lx][ly + i];
}

// grid(2048) = 256 s-pairs x 8 k-eighths; 32 waves/CU. (R21's version, 7.7us warm.)
__global__ __launch_bounds__(256) void k_gemm(const float* __restrict__ xT,
                                              const float* __restrict__ W1,
                                              float* __restrict__ part) {
    const int bx = blockIdx.x;        // 0..2047
    const int sp = bx >> 3;           // s-pair 0..255
    const int ke = bx & 7;            // k-eighth 0..7 (== XCD, matches writer)
    const int t  = threadIdx.x;

    const int r0 = 2 * sp, r1 = 2 * sp + 1;
    const int r2 = DR + 2 * sp, r3 = DR + 2 * sp + 1;

    const f4* __restrict__ W0 = reinterpret_cast<const f4*>(W1 + r0 * DM + ke * 64);
    const f4* __restrict__ Wp = reinterpret_cast<const f4*>(W1 + r1 * DM + ke * 64);
    const f4* __restrict__ W2 = reinterpret_cast<const f4*>(W1 + r2 * DM + ke * 64);
    const f4* __restrict__ W3 = reinterpret_cast<const f4*>(W1 + r3 * DM + ke * 64);
    const float* __restrict__ xb = xT + (ke * 64) * S_LEN + t;

    float a0 = 0.f, a1 = 0.f, a2 = 0.f, a3 = 0.f;

#pragma unroll 4
    for (int kk = 0; kk < 16; ++kk) {
        const float x0 = xb[(4 * kk + 0) * S_LEN];   // coalesced (lane = t)
        const float x1 = xb[(4 * kk + 1) * S_LEN];
        const float x2 = xb[(4 * kk + 2) * S_LEN];
        const float x3 = xb[(4 * kk + 3) * S_LEN];
        const f4 w0 = W0[kk];                        // wave-uniform -> s_load
        const f4 w1 = Wp[kk];
        const f4 w2 = W2[kk];
        const f4 w3 = W3[kk];
        a0 = fmaf(x0, w0.x, a0); a0 = fmaf(x1, w0.y, a0);
        a0 = fmaf(x2, w0.z, a0); a0 = fmaf(x3, w0.w, a0);
        a1 = fmaf(x0, w1.x, a1); a1 = fmaf(x1, w1.y, a1);
        a1 = fmaf(x2, w1.z, a1); a1 = fmaf(x3, w1.w, a1);
        a2 = fmaf(x0, w2.x, a2); a2 = fmaf(x1, w2.y, a2);
        a2 = fmaf(x2, w2.z, a2); a2 = fmaf(x3, w2.w, a2);
        a3 = fmaf(x0, w3.x, a3); a3 = fmaf(x1, w3.y, a3);
        a3 = fmaf(x2, w3.z, a3); a3 = fmaf(x3, w3.w, a3);
    }

    float* __restrict__ pb = part + ke * (1024 * 256);
    pb[r0 * 256 + t] = a0;                           // coalesced
    pb[r1 * 256 + t] = a1;
    pb[r2 * 256 + t] = a2;
    pb[r3 * 256 + t] = a3;
}

// grid(256) x 256: R21's k_rec verbatim (43.9us measured: folded 8-partial
// reduction + activation epilogue, then the ~6.15 TB/s y-stream).
__global__ __launch_bounds__(256) void k_rec(const float* __restrict__ x,
                                             const float* __restrict__ state0,
                                             const float* __restrict__ part,
                                             const float* __restrict__ b1,
                                             const float* __restrict__ Lam,
                                             f4* __restrict__ out4) {
    const int bx   = blockIdx.x;
    const int sp   = (bx & 7) * 32 + (bx >> 3);   // bijective XCD s-banding
    const int tid  = threadIdx.x;
    const int half = tid >> 7;           // 0 or 1
    const int s    = sp * 2 + half;
    const int dq   = tid & 127;          // d/4

    __shared__ f2 ac_l[2][S_LEN];        // {a, c} per (half, t)

    // ---- folded act: reduce 8 k-partials + activations -> ac_l ----
    const int P = 1024 * 256;
#pragma unroll
    for (int sl = 0; sl < 2; ++sl) {
        const int srow = sp * 2 + sl;
        float pi = b1[srow];
        float pr = b1[DR + srow];
#pragma unroll
        for (int e = 0; e < 8; ++e) {
            pi += part[e * P + srow * 256 + tid];          // coalesced
            pr += part[e * P + (DR + srow) * 256 + tid];
        }
        const float inp = 1.f / (1.f + expf(-pi));         // sigmoid
        const float rec = 1.f / (1.f + expf(-pr));         // sigmoid
        const float sof = log1pf(expf(Lam[srow]));         // softplus
        const float a   = expf(-8.f * sof * rec);
        const float c   = sqrtf(fmaxf(1.f - a * a, 0.f)) * inp;
        f2 ac; ac.x = a; ac.y = c;
        ac_l[sl][tid] = ac;
    }

    const f4* __restrict__ st4 = reinterpret_cast<const f4*>(state0);
    f4 h = st4[s * 128 + dq];

    const f4* __restrict__ x4 = reinterpret_cast<const f4*>(x);
    f4 xv = x4[dq];                      // t = 0 prefetch

    __syncthreads();                     // ac_l ready

#pragma unroll 4
    for (int t = 0; t < S_LEN; ++t) {
        f4 xn;
        if (t + 1 < S_LEN) xn = x4[(t + 1) * 128 + dq];
        else xn = (f4)0.f;

        const f2 ac = ac_l[half][t];               // LDS broadcast (wave-uniform)
        const float at = ac.x, ct = ac.y;
        h.x = fmaf(at, h.x, ct * xv.x);
        h.y = fmaf(at, h.y, ct * xv.y);
        h.z = fmaf(at, h.z, ct * xv.z);
        h.w = fmaf(at, h.w, ct * xv.w);

        __builtin_nontemporal_store(h, &out4[(t * DR + s) * 128 + dq]);
        xv = xn;
    }
    // final state
    out4[(S_LEN * DR) * 128 + s * 128 + dq] = h;
}

extern "C" void kernel_launch(void* const* d_in, const int* in_sizes, int n_in,
                              void* d_out, int out_size, void* d_ws, size_t ws_size,
                              hipStream_t stream) {
    const float* x      = (const float*)d_in[0];
    const float* state0 = (const float*)d_in[1];
    const float* W1     = (const float*)d_in[2];
    const float* b1     = (const float*)d_in[3];
    const float* Lam    = (const float*)d_in[4];

    float* ws   = (float*)d_ws;
    float* xT   = ws;                       // 131072 floats
    float* part = ws + 131072;              // 2097152 floats

    f4* out4 = (f4*)d_out;

    k_transpose_x<<<dim3(128), 256, 0, stream>>>(x, xT);
    k_gemm<<<dim3(2048), 256, 0, stream>>>(xT, W1, part);
    k_rec<<<dim3(256), 256, 0, stream>>>(x, state0, part, b1, Lam, out4);
}